// Round 5
// baseline (550.982 us; speedup 1.0000x reference)
//
#include <hip/hip_runtime.h>
#include <math.h>
#include <stdint.h>

// Bayesian DAG marginal propagation, N=4096, K=14 parents, C=2^14 configs.
//
// v7: 512 blocks x 512 threads (2 blocks/CU, SAFELY) + dual-pass fold.
//
// v6 post-mortem: register-level poll pipelining REGRESSED (256 vs 239 us)
// -- compiler emits s_waitcnt vmcnt(0) before the ballot/consume, so each
// spin iteration waits on the just-issued load regardless of pipeline
// depth. Both poll pipelines reverted to v3's simple dependent-load spin.
//
// Structural lever: block-serial slack. 256 blocks x 16 rounds means a
// chain child's block is often busy with an earlier node when its last
// parent lands. 512 x 512-thr blocks halves rounds (8) and doubles
// nodes-in-flight; co-residency needs only 1024 thr/CU (50%) and
// VGPR <= 128 (__launch_bounds__(512,4) enforces) -- a much weaker
// requirement than v4's failed 1024-thr x 2/CU. Host still queries
// occupancy and falls back to 256 blocks (same kernel, gridDim-strided)
// rather than ever launching a non-resident cooperative grid.
//
// Straggler handling simplified via multilinearity: S is multilinear in
// the 14 parent probs, so run the ENTIRE fold twice -- pass A with
// p[straggler]:=0, pass B with p[straggler]:=1 -- then
// res = fma(ps, B-A, A). Exact, uniform, no tier-specific switch; the
// doubled fold is off the critical path (hidden under the straggler wait).
// Critical tail stays: poll straggler + ONE fma + store.
//
// c = m*512 + wv*64 + lane; configs[c][j] = bit (13-j) of c, so:
//   lane bit t (0..5) <-> parent 13-t ; wv bit t (0..2) <-> parent 7-t ;
//   m bit j (0..4)    <-> parent 4-j.
//
// Flag word IS the payload (parent marginal probability; children clip to
// [1e-6, 1-1e-6] reproducing the reference's log-space clip chain).
// Sentinel 0x7F7F7F7F = 3.39e38 unreachable. Flags are monotone
// (SENTIN -> final value, written once). Relaxed agent-scope atomics.

#define NN     4096
#define KK     14
#define CC     16384
#define NROOTS 64
#define NTHR   512
#define NW     (NTHR / 64)   // 8 waves
#define PT     (CC / NTHR)   // 32 elements per thread
#define SENTIN 0x7F7F7F7Fu

// FOLD2(p, x0, x1): x0 = partial with this config bit = 0, x1 = bit = 1.
#define FOLD2(p, x0, x1) fmaf((p), (x1) - (x0), (x0))

#define LDFLAG(p) __hip_atomic_load(&flagv[(p)], __ATOMIC_RELAXED, \
                                    __HIP_MEMORY_SCOPE_AGENT)

// Full register-tier (5 levels, parents P[4]..P[0]) + lane-tier (6 levels,
// parents P[13]..P[8]) fold. All indices compile-time constant.
#define DO_FOLD(P, SRC, OUTACC)                                         \
    {                                                                   \
        float t16[16];                                                  \
        _Pragma("unroll") for (int i = 0; i < 16; ++i)                  \
            t16[i] = FOLD2((P)[4], (SRC)[2*i], (SRC)[2*i+1]);           \
        float t8[8];                                                    \
        _Pragma("unroll") for (int i = 0; i < 8; ++i)                   \
            t8[i] = FOLD2((P)[3], t16[2*i], t16[2*i+1]);                \
        float t4[4];                                                    \
        _Pragma("unroll") for (int i = 0; i < 4; ++i)                   \
            t4[i] = FOLD2((P)[2], t8[2*i], t8[2*i+1]);                  \
        float t2[2];                                                    \
        _Pragma("unroll") for (int i = 0; i < 2; ++i)                   \
            t2[i] = FOLD2((P)[1], t4[2*i], t4[2*i+1]);                  \
        float a = FOLD2((P)[0], t2[0], t2[1]);                          \
        _Pragma("unroll") for (int t = 0; t < 6; ++t) {                 \
            float other = __shfl_xor(a, 1 << t, 64);                    \
            bool  bit   = (lane >> t) & 1;                              \
            float lo = bit ? other : a;                                 \
            float hi = bit ? a : other;                                 \
            a = fmaf((P)[13 - t], hi - lo, lo);                         \
        }                                                               \
        OUTACC = a;                                                     \
    }

__global__ __launch_bounds__(NTHR, 4) void bayes_dag_kernel(
    const float* __restrict__ logits,
    const int*   __restrict__ parents,
    float*       __restrict__ out,
    unsigned*    __restrict__ flagv)   // N words: float bits of marginal prob
{
    __shared__ float pvals[KK];      // clipped parent probabilities
    __shared__ int   sSlotLds;       // straggler slot (0..13) or -1
    __shared__ float redA[NW];       // per-wave partial, pass A (p_s = 0)
    __shared__ float redB[NW];       // per-wave partial, pass B (p_s = 1)

    const int tid   = threadIdx.x;
    const int lane  = tid & 63;
    const int wv    = tid >> 6;
    const int gstep = gridDim.x;     // 512 (2 blocks/CU) or 256 (fallback)
    const float LOG2E = 1.4426950408889634f;

    int node = blockIdx.x;
    if (node < NROOTS) {
        if (tid == 0) {
            float x = logits[(size_t)node * CC];
            float p = __builtin_amdgcn_rcpf(1.f + exp2f(-x * LOG2E));
            __hip_atomic_store(&flagv[node], __float_as_uint(p),
                               __ATOMIC_RELAXED, __HIP_MEMORY_SCOPE_AGENT);
            out[node] = p;
        }
        node += gstep;
    }

    // preload first row: c = m*NTHR + tid (fully coalesced dwords)
    float xn[PT];
    {
        const float* row = logits + (size_t)node * CC;
        #pragma unroll
        for (int m = 0; m < PT; ++m) xn[m] = row[m * NTHR + tid];
    }
    // wave 0 keeps its parent indices in registers (lane k holds parent k)
    int pcur = 0;
    if (wv == 0 && lane < KK) pcur = parents[node * KK + lane];

    for (; node < NN; node += gstep) {
        const int nxt    = node + gstep;
        const int nclamp = (nxt < NN) ? nxt : node;

        // ---- consume current row (sigmoid), then reuse xn for the next
        //      row's prefetch (in flight during spin + fold + next round) ----
        float sig[PT];
        #pragma unroll
        for (int m = 0; m < PT; ++m)
            sig[m] = __builtin_amdgcn_rcpf(1.f + exp2f(-xn[m] * LOG2E));

        const float* nrow = logits + (size_t)nclamp * CC;
        #pragma unroll
        for (int m = 0; m < PT; ++m) xn[m] = nrow[m * NTHR + tid];

        // ---- wave 0: spin until >=13 of 14 parents ready; find straggler ----
        int spLoc = 0;                       // straggler parent node (wave 0)
        if (wv == 0) {
            unsigned v = SENTIN;
            unsigned long long rdy;
            int guard = 0;
            for (;;) {
                if (lane < KK && v == SENTIN)
                    v = LDFLAG(pcur);
                rdy = __ballot(lane >= KK || v != SENTIN);
                if (__popcll(rdy) >= 63) break;      // <=1 parent missing
                if (++guard > (1 << 22)) break;      // visible-failure escape
            }
            unsigned long long miss = (~rdy) & 0x3FFFull;
            int s = miss ? __builtin_ctzll(miss) : -1;
            spLoc = __shfl(pcur, (s < 0) ? 0 : s, 64);
            if (lane == 0) sSlotLds = s;
            if (lane < KK) {
                float pf = __uint_as_float(v);   // straggler lane: garbage, substituted below
                pvals[lane] = fminf(fmaxf(pf, 1e-6f), 1.f - 1e-6f);
            }
            // prefetch next node's parent indices (lands during fold)
            if (lane < KK) pcur = parents[nclamp * KK + lane];
        }
        __syncthreads();

        const int s = sSlotLds;
        // multilinear dual-pass: pass A has p_s := 0, pass B has p_s := 1.
        // (s < 0: pA == pB, passes identical, res = A.)
        float pA[KK], pB[KK];
        #pragma unroll
        for (int k = 0; k < KK; ++k) {
            float v = pvals[k];
            pA[k] = (k == s) ? 0.f : v;
            pB[k] = (k == s) ? 1.f : v;
        }

        float accA, accB;
        DO_FOLD(pA, sig, accA);
        DO_FOLD(pB, sig, accB);
        if (lane == 0) { redA[wv] = accA; redB[wv] = accB; }
        __syncthreads();

        // ---- wave-tier folds (3 levels, parents P[7..5]) + final ----
        if (wv == 0) {
            float vA = (lane < NW) ? redA[lane] : 0.f;
            float vB = (lane < NW) ? redB[lane] : 0.f;
            #pragma unroll
            for (int t = 0; t < 3; ++t) {
                {
                    float other = __shfl_xor(vA, 1 << t, 64);
                    bool  bit   = (lane >> t) & 1;
                    float lo = bit ? other : vA;
                    float hi = bit ? vA : other;
                    vA = fmaf(pA[7 - t], hi - lo, lo);
                }
                {
                    float other = __shfl_xor(vB, 1 << t, 64);
                    bool  bit   = (lane >> t) & 1;
                    float lo = bit ? other : vB;
                    float hi = bit ? vB : other;
                    vB = fmaf(pB[7 - t], hi - lo, lo);
                }
            }
            float res;
            if (s < 0) {
                res = vA;                       // all 14 folded already
            } else {
                // v3-style simple poll (pipelining regressed, v6)
                unsigned u = LDFLAG(spLoc);
                int guard = 0;
                while (u == SENTIN && ++guard < (1 << 23))
                    u = LDFLAG(spLoc);
                float ps = fminf(fmaxf(__uint_as_float(u), 1e-6f), 1.f - 1e-6f);
                res = fmaf(ps, vB - vA, vA);    // ONE fma on the critical path
            }
            if (lane == 0) {
                __hip_atomic_store(&flagv[node], __float_as_uint(res),
                                   __ATOMIC_RELAXED, __HIP_MEMORY_SCOPE_AGENT);
                out[node] = res;                // flag first: it's the consumer
            }
        }
        // (xn prefetch keeps flowing; its vmcnt wait is at next round's sigmoid)
    }
}

extern "C" void kernel_launch(void* const* d_in, const int* in_sizes, int n_in,
                              void* d_out, int out_size, void* d_ws, size_t ws_size,
                              hipStream_t stream) {
    const float* logits  = (const float*)d_in[0];
    // d_in[1] = configs — encoded analytically in the fold order, unused
    const int*   parents = (const int*)d_in[2];
    // d_in[3] = root_mask — node < 64, unused
    float*    out   = (float*)d_out;
    unsigned* flagv = (unsigned*)d_ws;   // N words

    // 512 blocks iff 2 blocks/CU genuinely fit (v4 lesson: never launch a
    // cooperative grid that isn't provably co-resident). Host query only,
    // no stream ops -> graph-capture safe. Cached.
    static int grid = 0;
    if (grid == 0) {
        int maxb = 0;
        hipError_t e = hipOccupancyMaxActiveBlocksPerMultiprocessor(
            &maxb, (const void*)bayes_dag_kernel, NTHR, 0);
        grid = (e == hipSuccess && maxb >= 2) ? 512 : 256;
    }

    hipMemsetAsync(flagv, 0x7F, NN * sizeof(unsigned), stream);

    void* args[] = { (void*)&logits, (void*)&parents, (void*)&out, (void*)&flagv };
    hipLaunchCooperativeKernel((const void*)bayes_dag_kernel,
                               dim3(grid), dim3(NTHR), args, 0, stream);
}

// Round 6
// 511.440 us; speedup vs baseline: 1.0773x; 1.0773x over previous
//
#include <hip/hip_runtime.h>
#include <math.h>
#include <stdint.h>

// Bayesian DAG marginal propagation, N=4096, K=14 parents, C=2^14 configs.
//
// v8 = v3 geometry/fold (known-good 239 us, 1024 thr, PT=16, no spills)
//      + role-alternating wave overlap of {straggler-poll(r)} with
//        {13-of-14 spin(r+1)}.
//
// v7 post-mortem: PT=32 spilled (WRITE_SIZE 263KB -> 31MB = scratch) and
// dual-pass fold doubled VALU; 277 us. Reverted. v6 post-mortem: source-
// level poll pipelining defeated by compiler vmcnt(0); reverted.
//
// v8's lever: in v3 the per-round serial path is
//   spin(13of14, r) -> fold(r) -> straggler-poll(r) -> store(r) -> spin(r+1)
// i.e. TWO wait segments in series per round, but they are independent
// events. Waves 0 and 1 alternate roles per round parity:
//   round r tail: wave rp   = finisher(r): cross-fold + straggler poll +
//                             fma + store (it spun node r last round and
//                             holds straggler slot/addr in registers);
//                 wave rp^1 = spinner(r+1): 13-of-14 spin for node r+1,
//                             publishes pvals[rp^1]/sSlot[rp^1].
// The two waits run concurrently -> max() instead of sum. pvals/sSlot are
// double-buffered by parity; barriers stay 2/round; every wave reaches
// every barrier (no sub-block sync, no deadlock surface).
//
// Flag word IS the payload (parent marginal probability; children clip to
// [1e-6, 1-1e-6] reproducing the reference's log-space clip chain).
// Sentinel 0x7F7F7F7F = 3.39e38 unreachable. Flags are monotone
// (SENTIN -> final value, written once). Relaxed agent-scope atomics.

#define NN     4096
#define KK     14
#define CC     16384
#define NROOTS 64
#define NBLK   256
#define NTHR   1024
#define NW     (NTHR / 64)   // 16 waves
#define PT     (CC / NTHR)   // 16 elements per thread
#define SENTIN 0x7F7F7F7Fu

// FOLD2(p, x0, x1): x0 = partial with this config bit = 0, x1 = bit = 1.
#define FOLD2(p, x0, x1) fmaf((p), (x1) - (x0), (x0))
// Fold 8 values over 3 bits; pA = lowest-stride bit's parent, then pB, pC.
#define FOLD8(pA, pB, pC, s0,s1,s2,s3,s4,s5,s6,s7) \
    FOLD2(pC, FOLD2(pB, FOLD2(pA, s0, s1), FOLD2(pA, s2, s3)), \
              FOLD2(pB, FOLD2(pA, s4, s5), FOLD2(pA, s6, s7)))

#define LDFLAG(p) __hip_atomic_load(&flagv[(p)], __ATOMIC_RELAXED, \
                                    __HIP_MEMORY_SCOPE_AGENT)

__global__ __launch_bounds__(NTHR, 4) void bayes_dag_kernel(
    const float* __restrict__ logits,
    const int*   __restrict__ parents,
    float*       __restrict__ out,
    unsigned*    __restrict__ flagv)   // N words: float bits of marginal prob
{
    __shared__ float pvals[2][KK];    // clipped parent probs, by round parity
    __shared__ int   sSlot[2];        // straggler slot (0..13) or -1, by parity
    __shared__ float redA[NW];        // per-wave partial (straggler bit=0)
    __shared__ float redB[NW];        // per-wave partial (straggler bit=1)

    const int tid  = threadIdx.x;
    const int lane = tid & 63;
    const int wv   = tid >> 6;
    const float LOG2E = 1.4426950408889634f;

    int node = blockIdx.x;
    if (node < NROOTS) {
        if (tid == 0) {
            float x = logits[(size_t)node * CC];
            float p = __builtin_amdgcn_rcpf(1.f + exp2f(-x * LOG2E));
            __hip_atomic_store(&flagv[node], __float_as_uint(p),
                               __ATOMIC_RELAXED, __HIP_MEMORY_SCOPE_AGENT);
            out[node] = p;
        }
        node += NBLK;
    }

    // ---- setup: sig for first node, prefetch second node's row ----
    float sig[PT];
    {
        const float* row = logits + (size_t)node * CC;
        float xt[PT];
        #pragma unroll
        for (int m = 0; m < PT; ++m) xt[m] = row[m * NTHR + tid];
        #pragma unroll
        for (int m = 0; m < PT; ++m)
            sig[m] = __builtin_amdgcn_rcpf(1.f + exp2f(-xt[m] * LOG2E));
    }
    float xn[PT];
    {
        int n1 = node + NBLK; if (n1 >= NN) n1 = node;
        const float* row = logits + (size_t)n1 * CC;
        #pragma unroll
        for (int m = 0; m < PT; ++m) xn[m] = row[m * NTHR + tid];
    }

    // Waves 0/1 hold parent indices for their next assigned node (lane k
    // holds parent k) and the straggler slot/addr from their last spin.
    int pcur = 0, myS = -1, mySp = 0;
    if (wv == 0) {
        // pre-loop spin for the block's first folded node (round 0 finisher)
        if (lane < KK) pcur = parents[node * KK + lane];
        unsigned v = SENTIN; unsigned long long rdy; int guard = 0;
        for (;;) {
            if (lane < KK && v == SENTIN) v = LDFLAG(pcur);
            rdy = __ballot(lane >= KK || v != SENTIN);
            if (__popcll(rdy) >= 63) break;          // <=1 parent missing
            if (++guard > (1 << 22)) break;          // visible-failure escape
        }
        unsigned long long miss = (~rdy) & 0x3FFFull;
        myS  = miss ? __builtin_ctzll(miss) : -1;
        mySp = __shfl(pcur, (myS < 0) ? 0 : myS, 64);
        if (lane == 0) sSlot[0] = myS;
        if (lane < KK) {
            float pf = __uint_as_float(v);           // straggler lane: never read
            pvals[0][lane] = fminf(fmaxf(pf, 1e-6f), 1.f - 1e-6f);
        }
        int pn = node + 2 * NBLK; if (pn >= NN) pn = node;   // wave0's next spin
        if (lane < KK) pcur = parents[pn * KK + lane];
    } else if (wv == 1) {
        int pn = node + NBLK; if (pn >= NN) pn = node;       // wave1 spins round 1's node
        if (lane < KK) pcur = parents[pn * KK + lane];
    }
    __syncthreads();

    int rp = 0;
    for (; node < NN; node += NBLK, rp ^= 1) {
        const int s = sSlot[rp];
        float pv[KK];
        #pragma unroll
        for (int k = 0; k < KK; ++k) pv[k] = pvals[rp][k];

        // ---- register-tier folds: m bit j <-> c bit 10+j <-> parent 3-j ----
        // If straggler is parent 0..3, skip its bit: two half-folds -> pair.
        float acc, acc1 = 0.f;
        const bool regPair = (s >= 0 && s < 4);
        switch (s) {
            case 0:  // skip m bit 3
                acc  = FOLD8(pv[3],pv[2],pv[1], sig[0],sig[1],sig[2],sig[3],sig[4],sig[5],sig[6],sig[7]);
                acc1 = FOLD8(pv[3],pv[2],pv[1], sig[8],sig[9],sig[10],sig[11],sig[12],sig[13],sig[14],sig[15]);
                break;
            case 1:  // skip m bit 2
                acc  = FOLD8(pv[3],pv[2],pv[0], sig[0],sig[1],sig[2],sig[3],sig[8],sig[9],sig[10],sig[11]);
                acc1 = FOLD8(pv[3],pv[2],pv[0], sig[4],sig[5],sig[6],sig[7],sig[12],sig[13],sig[14],sig[15]);
                break;
            case 2:  // skip m bit 1
                acc  = FOLD8(pv[3],pv[1],pv[0], sig[0],sig[1],sig[4],sig[5],sig[8],sig[9],sig[12],sig[13]);
                acc1 = FOLD8(pv[3],pv[1],pv[0], sig[2],sig[3],sig[6],sig[7],sig[10],sig[11],sig[14],sig[15]);
                break;
            case 3:  // skip m bit 0
                acc  = FOLD8(pv[2],pv[1],pv[0], sig[0],sig[2],sig[4],sig[6],sig[8],sig[10],sig[12],sig[14]);
                acc1 = FOLD8(pv[2],pv[1],pv[0], sig[1],sig[3],sig[5],sig[7],sig[9],sig[11],sig[13],sig[15]);
                break;
            default: // full 4-level fold (straggler elsewhere, or none)
                acc = FOLD2(pv[0],
                        FOLD8(pv[3],pv[2],pv[1], sig[0],sig[1],sig[2],sig[3],sig[4],sig[5],sig[6],sig[7]),
                        FOLD8(pv[3],pv[2],pv[1], sig[8],sig[9],sig[10],sig[11],sig[12],sig[13],sig[14],sig[15]));
                break;
        }

        // ---- lane-tier folds: lane bit t <-> c bit t <-> parent 13-t ----
        const int st = (s >= 8) ? (13 - s) : -1;   // lane bit to skip
        #pragma unroll
        for (int t = 0; t < 6; ++t) {
            if (t == st) continue;                 // block-uniform branch
            const float p = pv[13 - t];
            {
                float other = __shfl_xor(acc, 1 << t, 64);
                bool  bit   = (lane >> t) & 1;
                float a = bit ? other : acc;
                float b = bit ? acc : other;
                acc = fmaf(p, b - a, a);
            }
            if (regPair) {
                float other = __shfl_xor(acc1, 1 << t, 64);
                bool  bit   = (lane >> t) & 1;
                float a = bit ? other : acc1;
                float b = bit ? acc1 : other;
                acc1 = fmaf(p, b - a, a);
            }
        }

        // publish per-wave partial(s)
        if (regPair) {
            if (lane == 0) { redA[wv] = acc; redB[wv] = acc1; }
        } else if (st >= 0) {
            if (lane == 0)         redA[wv] = acc;   // straggler bit = 0
            if (lane == (1 << st)) redB[wv] = acc;   // straggler bit = 1
        } else {
            if (lane == 0) redA[wv] = acc;
        }
        __syncthreads();                             // barrier A

        const int node2 = node + NBLK;

        if (wv == rp) {
            // ===== finisher(node): cross-fold + straggler poll + store =====
            const bool pairAB = (s >= 0) && (s < 4 || s >= 8);
            const int  tw     = (s >= 4 && s < 8) ? (7 - s) : -1;
            float v0 = (lane < NW) ? redA[lane] : 0.f;
            float v1 = (pairAB && lane < NW) ? redB[lane] : 0.f;
            #pragma unroll
            for (int t = 0; t < 4; ++t) {
                if (t == tw) continue;
                const float p = pv[7 - t];
                {
                    float other = __shfl_xor(v0, 1 << t, 64);
                    bool  bit   = (lane >> t) & 1;
                    float a = bit ? other : v0;
                    float b = bit ? v0 : other;
                    v0 = fmaf(p, b - a, a);
                }
                if (pairAB) {
                    float other = __shfl_xor(v1, 1 << t, 64);
                    bool  bit   = (lane >> t) & 1;
                    float a = bit ? other : v1;
                    float b = bit ? v1 : other;
                    v1 = fmaf(p, b - a, a);
                }
            }
            float res;
            if (s < 0) {
                res = v0;                            // all 14 folded already
            } else {
                float x0, x1;
                if (tw >= 0) { x0 = __shfl(v0, 0, 64); x1 = __shfl(v0, 1 << tw, 64); }
                else         { x0 = v0; x1 = v1; }   // valid at lane 0
                unsigned u = LDFLAG(mySp);
                int guard = 0;
                while (u == SENTIN && ++guard < (1 << 23))
                    u = LDFLAG(mySp);
                float ps = fminf(fmaxf(__uint_as_float(u), 1e-6f), 1.f - 1e-6f);
                res = fmaf(ps, x1 - x0, x0);         // ONE fma on the critical path
            }
            if (lane == 0) {
                __hip_atomic_store(&flagv[node], __float_as_uint(res),
                                   __ATOMIC_RELAXED, __HIP_MEMORY_SCOPE_AGENT);
                out[node] = res;                     // flag first: it's the consumer
            }
        } else if (wv == (rp ^ 1) && node2 < NN) {
            // ===== spinner(node2): 13-of-14 spin, runs DURING finisher's wait =====
            unsigned v = SENTIN; unsigned long long rdy; int guard = 0;
            for (;;) {
                if (lane < KK && v == SENTIN) v = LDFLAG(pcur);
                rdy = __ballot(lane >= KK || v != SENTIN);
                if (__popcll(rdy) >= 63) break;      // <=1 parent missing
                if (++guard > (1 << 22)) break;      // visible-failure escape
            }
            unsigned long long miss = (~rdy) & 0x3FFFull;
            myS  = miss ? __builtin_ctzll(miss) : -1;
            mySp = __shfl(pcur, (myS < 0) ? 0 : myS, 64);
            if (lane == 0) sSlot[rp ^ 1] = myS;
            if (lane < KK) {
                float pf = __uint_as_float(v);       // straggler lane: never read
                pvals[rp ^ 1][lane] = fminf(fmaxf(pf, 1e-6f), 1.f - 1e-6f);
            }
            int pn = node + 3 * NBLK; if (pn >= NN) pn = node;   // this wave's next spin
            if (lane < KK) pcur = parents[pn * KK + lane];
        }

        // ---- all waves: sigmoid for node2 from xn; prefetch x(node+512) ----
        #pragma unroll
        for (int m = 0; m < PT; ++m)
            sig[m] = __builtin_amdgcn_rcpf(1.f + exp2f(-xn[m] * LOG2E));
        {
            int n2 = node + 2 * NBLK; if (n2 >= NN) n2 = node;
            const float* row = logits + (size_t)n2 * CC;
            #pragma unroll
            for (int m = 0; m < PT; ++m) xn[m] = row[m * NTHR + tid];
        }
        __syncthreads();                             // barrier B
    }
}

extern "C" void kernel_launch(void* const* d_in, const int* in_sizes, int n_in,
                              void* d_out, int out_size, void* d_ws, size_t ws_size,
                              hipStream_t stream) {
    const float* logits  = (const float*)d_in[0];
    // d_in[1] = configs — encoded analytically in the fold order, unused
    const int*   parents = (const int*)d_in[2];
    // d_in[3] = root_mask — node < 64, unused
    float*    out   = (float*)d_out;
    unsigned* flagv = (unsigned*)d_ws;   // N words

    hipMemsetAsync(flagv, 0x7F, NN * sizeof(unsigned), stream);

    void* args[] = { (void*)&logits, (void*)&parents, (void*)&out, (void*)&flagv };
    hipLaunchCooperativeKernel((const void*)bayes_dag_kernel,
                               dim3(NBLK), dim3(NTHR), args, 0, stream);
}